// Round 9
// baseline (127.721 us; speedup 1.0000x reference)
//
#include <hip/hip_runtime.h>

#define T 256
#define H 512
#define EPSF 1e-5f

__device__ __forceinline__ float block_sum(float v, float* s4) {
    for (int o = 32; o; o >>= 1) v += __shfl_xor(v, o);
    int w = threadIdx.x >> 6;
    __syncthreads();
    if ((threadIdx.x & 63) == 0) s4[w] = v;
    __syncthreads();
    return s4[0] + s4[1] + s4[2] + s4[3];
}

// 1024-thread block sum (16 waves)
__device__ __forceinline__ float bsum16(float v, float* s16) {
    for (int o = 32; o; o >>= 1) v += __shfl_xor(v, o);
    int w = threadIdx.x >> 6;
    __syncthreads();
    if ((threadIdx.x & 63) == 0) s16[w] = v;
    __syncthreads();
    float r = 0.f;
    #pragma unroll
    for (int i = 0; i < 16; ++i) r += s16[i];
    return r;
}

// bid 0..7: S-scan (two-pass, 64 cols/block, wave = 64-t chunk).
// bid 8..1031: Z=relu(h@U+a), HZ=h.*Z, c. Tile 1t x 64 float2-cols, K-split-4.
__global__ __launch_bounds__(256) void k1(
        const float* __restrict__ h, const float* __restrict__ U,
        const float* __restrict__ a, float* __restrict__ Z,
        float* __restrict__ HZ, float* __restrict__ c, float* __restrict__ S) {
    int bid = blockIdx.x, tid = threadIdx.x;
    int lane = tid & 63, w = tid >> 6;
    if (bid < 8) {
        __shared__ float csum[4][64];
        int q = bid * 64 + lane;
        int tbase = w * 64;
        float s = 0.f;
        for (int j = 0; j < 64; j += 8) {
            float v[8];
            #pragma unroll
            for (int u = 0; u < 8; ++u) v[u] = h[(tbase + j + u) * H + q];
            #pragma unroll
            for (int u = 0; u < 8; ++u) s += v[u];
        }
        csum[w][lane] = s;
        __syncthreads();
        float acc = 0.f;
        #pragma unroll
        for (int w2 = 0; w2 < 3; ++w2) if (w2 < w) acc += csum[w2][lane];
        for (int j = 0; j < 64; j += 8) {
            float v[8];
            #pragma unroll
            for (int u = 0; u < 8; ++u) v[u] = h[(tbase + j + u) * H + q];
            #pragma unroll
            for (int u = 0; u < 8; ++u) { acc += v[u]; S[(tbase + j + u) * H + q] = acc; }
        }
        return;
    }
    int b = bid - 8;                 // 0..1023
    int t = b >> 2, qt = b & 3;
    __shared__ __align__(16) float sh[512];
    __shared__ float2 part[3][64];
    ((float2*)sh)[tid] = ((const float2*)(h + t * H))[tid];
    __syncthreads();

    if (qt == 0 && w == 0) {         // c[t] once per row
        float s = 0.f;
        #pragma unroll
        for (int j = 0; j < 8; ++j) s += sh[lane + j * 64];
        for (int o = 32; o; o >>= 1) s += __shfl_xor(s, o);
        if (lane == 0) c[t] = s;
    }

    int qc = qt * 64 + lane;
    const float2* U2 = (const float2*)U;
    float2 acc = {0.f, 0.f};
    int kbeg = w * 128;
    for (int k0 = kbeg; k0 < kbeg + 128; k0 += 16) {
        float2 bv[16]; float av[16];
        #pragma unroll
        for (int u = 0; u < 16; ++u) bv[u] = U2[(k0 + u) * 256 + qc];
        #pragma unroll
        for (int u = 0; u < 16; ++u) av[u] = sh[k0 + u];
        #pragma unroll
        for (int u = 0; u < 16; ++u) { acc.x += av[u] * bv[u].x; acc.y += av[u] * bv[u].y; }
    }
    if (w) part[w - 1][lane] = acc;
    __syncthreads();
    if (w == 0) {
        #pragma unroll
        for (int p = 0; p < 3; ++p) { acc.x += part[p][lane].x; acc.y += part[p][lane].y; }
        float2 av = ((const float2*)a)[qc];
        float zx = fmaxf(acc.x + av.x, 0.f), zy = fmaxf(acc.y + av.y, 0.f);
        float2 hv = ((float2*)sh)[qc];
        ((float2*)Z)[t * 256 + qc]  = make_float2(zx, zy);
        ((float2*)HZ)[t * 256 + qc] = make_float2(hv.x * zx, hv.y * zy);
    }
}

// bid 0..1023: u0 = Z@W + b (tile 1t x 64 float2, K-split-4).
// bid 1024..1551: Beta = tril(Z@HZ^T,-1)+c, compact triangular 8x8 tiles.
__global__ __launch_bounds__(256) void k2(
        const float* __restrict__ Z, const float* __restrict__ W,
        const float* __restrict__ bb, const float* __restrict__ HZ,
        const float* __restrict__ c, float* __restrict__ u0,
        float* __restrict__ Beta) {
    __shared__ __align__(16) float smem[2 * 8 * 516 + 256];
    int bid = blockIdx.x, tid = threadIdx.x;
    int lane = tid & 63, w = tid >> 6;
    if (bid < 1024) {
        float* sh = smem;                       // 512
        float2* part = (float2*)(smem + 512);   // [3][64]
        int t = bid >> 2, qt = bid & 3;
        ((float2*)sh)[tid] = ((const float2*)(Z + t * H))[tid];
        __syncthreads();
        int qc = qt * 64 + lane;
        const float2* W2 = (const float2*)W;
        float2 acc = {0.f, 0.f};
        int kbeg = w * 128;
        for (int k0 = kbeg; k0 < kbeg + 128; k0 += 16) {
            float2 bv[16]; float av[16];
            #pragma unroll
            for (int u = 0; u < 16; ++u) bv[u] = W2[(k0 + u) * 256 + qc];
            #pragma unroll
            for (int u = 0; u < 16; ++u) av[u] = sh[k0 + u];
            #pragma unroll
            for (int u = 0; u < 16; ++u) { acc.x += av[u] * bv[u].x; acc.y += av[u] * bv[u].y; }
        }
        if (w) part[(w - 1) * 64 + lane] = acc;
        __syncthreads();
        if (w == 0) {
            #pragma unroll
            for (int p = 0; p < 3; ++p) {
                float2 pv = part[p * 64 + lane];
                acc.x += pv.x; acc.y += pv.y;
            }
            float2 bv = ((const float2*)bb)[qc];
            ((float2*)u0)[t * 256 + qc] = make_float2(acc.x + bv.x, acc.y + bv.y);
        }
    } else {
        int e = bid - 1024;                        // 0..527 compact triangular
        int ti = (int)((sqrtf(8.f * (float)e + 1.f) - 1.f) * 0.5f);
        while ((ti + 1) * (ti + 2) / 2 <= e) ++ti;
        while (ti * (ti + 1) / 2 > e) --ti;
        int ii = e - ti * (ti + 1) / 2;
        int t0 = ti * 8, i0 = ii * 8;
        float* Zs = smem;                 // [8][516]
        float* Hs = smem + 8 * 516;       // [8][516]
        float* red = smem + 2 * 8 * 516;  // [4][64]
        #pragma unroll
        for (int j = 0; j < 4; ++j) {
            int idx = tid + j * 256;
            int row = idx >> 7, col4 = idx & 127;
            float4 v = ((const float4*)(Z + (t0 + row) * H))[col4];
            *(float4*)&Zs[row * 516 + col4 * 4] = v;
            float4 g = ((const float4*)(HZ + (i0 + row) * H))[col4];
            *(float4*)&Hs[row * 516 + col4 * 4] = g;
        }
        __syncthreads();
        int ks = tid >> 6, r = (tid >> 3) & 7, ci = tid & 7;
        float acc = 0.f;
        int kb = ks * 128;
        #pragma unroll 4
        for (int k0 = kb; k0 < kb + 128; k0 += 8) {
            float4 z0 = *(float4*)&Zs[r * 516 + k0];
            float4 z1 = *(float4*)&Zs[r * 516 + k0 + 4];
            float4 h0 = *(float4*)&Hs[ci * 516 + k0];
            float4 h1 = *(float4*)&Hs[ci * 516 + k0 + 4];
            acc += z0.x * h0.x + z0.y * h0.y + z0.z * h0.z + z0.w * h0.w
                 + z1.x * h1.x + z1.y * h1.y + z1.z * h1.z + z1.w * h1.w;
        }
        red[ks * 64 + r * 8 + ci] = acc;
        __syncthreads();
        if (tid < 64) {
            int r2 = tid >> 3, c2 = tid & 7;
            float v = red[tid] + red[64 + tid] + red[128 + tid] + red[192 + tid];
            int t = t0 + r2, i = i0 + c2;
            Beta[t * 256 + i] = (i < t) ? v + c[i] : 0.f;
        }
    }
}

// One wave (64 thr) per row t: y=LN(u0), g=softmax(y)-onehot, D=LN-bwd(g), SD=S.*D.
// All reductions are wave-level shuffles — zero barriers.
__global__ __launch_bounds__(64) void k3(
        const float* __restrict__ u0, const float* __restrict__ gamma,
        const float* __restrict__ beta, const int* __restrict__ targets,
        const float* __restrict__ S, float* __restrict__ D, float* __restrict__ SD) {
    int t = blockIdx.x, lane = threadIdx.x;
    const float2* u02 = (const float2*)(u0 + t * H);
    float2 uv[4], gv[4], bv[4];
    #pragma unroll
    for (int j = 0; j < 4; ++j) {
        int qc = lane + j * 64;
        uv[j] = u02[qc];
        gv[j] = ((const float2*)gamma)[qc];
        bv[j] = ((const float2*)beta)[qc];
    }
    float s1 = 0.f;
    #pragma unroll
    for (int j = 0; j < 4; ++j) s1 += uv[j].x + uv[j].y;
    for (int o = 32; o; o >>= 1) s1 += __shfl_xor(s1, o);
    float m = s1 * (1.f / H);

    float2 xh[4]; float vs = 0.f;
    #pragma unroll
    for (int j = 0; j < 4; ++j) {
        float d0 = uv[j].x - m, d1 = uv[j].y - m;
        vs += d0 * d0 + d1 * d1;
        xh[j] = make_float2(d0, d1);
    }
    for (int o = 32; o; o >>= 1) vs += __shfl_xor(vs, o);
    float s = rsqrtf(vs * (1.f / H) + EPSF);

    float2 y[4]; float ymax = -1e30f;
    #pragma unroll
    for (int j = 0; j < 4; ++j) {
        xh[j].x *= s; xh[j].y *= s;
        y[j].x = xh[j].x * gv[j].x + bv[j].x;
        y[j].y = xh[j].y * gv[j].y + bv[j].y;
        ymax = fmaxf(ymax, fmaxf(y[j].x, y[j].y));
    }
    for (int o = 32; o; o >>= 1) ymax = fmaxf(ymax, __shfl_xor(ymax, o));

    float2 ev[4]; float es = 0.f;
    #pragma unroll
    for (int j = 0; j < 4; ++j) {
        ev[j].x = __expf(y[j].x - ymax);
        ev[j].y = __expf(y[j].y - ymax);
        es += ev[j].x + ev[j].y;
    }
    for (int o = 32; o; o >>= 1) es += __shfl_xor(es, o);
    float invZ = 1.f / es;

    int tgt = targets[t];
    float2 gy[4]; float sgy = 0.f, sgx = 0.f;
    #pragma unroll
    for (int j = 0; j < 4; ++j) {
        int qc = lane + j * 64;
        float g0 = ev[j].x * invZ - (2 * qc == tgt ? 1.f : 0.f);
        float g1 = ev[j].y * invZ - (2 * qc + 1 == tgt ? 1.f : 0.f);
        gy[j].x = g0 * gv[j].x;
        gy[j].y = g1 * gv[j].y;
        sgy += gy[j].x + gy[j].y;
        sgx += gy[j].x * xh[j].x + gy[j].y * xh[j].y;
    }
    for (int o = 32; o; o >>= 1) sgy += __shfl_xor(sgy, o);
    for (int o = 32; o; o >>= 1) sgx += __shfl_xor(sgx, o);
    float mgy = sgy * (1.f / H), mgx = sgx * (1.f / H);

    #pragma unroll
    for (int j = 0; j < 4; ++j) {
        int qc = lane + j * 64;
        float dd0 = s * (gy[j].x - mgy - xh[j].x * mgx);
        float dd1 = s * (gy[j].y - mgy - xh[j].y * mgx);
        float2 sv = ((const float2*)S)[t * 256 + qc];
        ((float2*)D)[t * 256 + qc]  = make_float2(dd0, dd1);
        ((float2*)SD)[t * 256 + qc] = make_float2(sv.x * dd0, sv.y * dd1);
    }
}

// One block (1024 thr) per row t: 4 i-groups x 256 col-lanes compute
// A1 = Beta_t@D, A2 = Beta_t@SD; LDS-reduce; pre = u0 - S_t.*A1 + A2; out = LN(pre).
__global__ __launch_bounds__(1024) void k4(
        const float* __restrict__ Beta, const float* __restrict__ D,
        const float* __restrict__ SD, const float* __restrict__ u0,
        const float* __restrict__ S, const float* __restrict__ gamma,
        const float* __restrict__ beta, float* __restrict__ out) {
    __shared__ float Brow[256];
    __shared__ float r1[4][512];
    __shared__ float r2[4][512];
    __shared__ float s16[16];
    int t = blockIdx.x, tid = threadIdx.x;
    if (tid < 256) Brow[tid] = Beta[t * 256 + tid];
    __syncthreads();

    int ig = tid >> 8, qc = tid & 255;
    int ibeg = ig * 64;
    int iend = min((t + 7) & ~7, ibeg + 64);
    float2 a1 = {0.f, 0.f}, a2 = {0.f, 0.f};
    const float2* D2 = (const float2*)D;
    const float2* SD2 = (const float2*)SD;
    for (int k0 = ibeg; k0 < iend; k0 += 8) {
        float2 dv[8], sv[8];
        #pragma unroll
        for (int u = 0; u < 8; ++u) {
            dv[u] = D2[(k0 + u) * 256 + qc];
            sv[u] = SD2[(k0 + u) * 256 + qc];
        }
        #pragma unroll
        for (int u = 0; u < 8; ++u) {
            float bw = Brow[k0 + u];
            a1.x += bw * dv[u].x; a1.y += bw * dv[u].y;
            a2.x += bw * sv[u].x; a2.y += bw * sv[u].y;
        }
    }
    r1[ig][2 * qc] = a1.x; r1[ig][2 * qc + 1] = a1.y;
    r2[ig][2 * qc] = a2.x; r2[ig][2 * qc + 1] = a2.y;
    __syncthreads();

    float p = 0.f;
    if (tid < 512) {
        float A1 = r1[0][tid] + r1[1][tid] + r1[2][tid] + r1[3][tid];
        float A2 = r2[0][tid] + r2[1][tid] + r2[2][tid] + r2[3][tid];
        p = u0[t * H + tid] - S[t * H + tid] * A1 + A2;
    }
    float m = bsum16(p, s16) * (1.f / H);
    float d = (tid < 512) ? p - m : 0.f;
    float var = bsum16(d * d, s16) * (1.f / H);
    float s = rsqrtf(var + EPSF);
    if (tid < 512)
        out[t * H + tid] = d * s * gamma[tid] + beta[tid];
}

extern "C" void kernel_launch(void* const* d_in, const int* in_sizes, int n_in,
                              void* d_out, int out_size, void* d_ws, size_t ws_size,
                              hipStream_t stream) {
    const float* h     = (const float*)d_in[0];
    const float* U     = (const float*)d_in[1];
    const float* W     = (const float*)d_in[2];
    const float* a     = (const float*)d_in[3];
    const float* b     = (const float*)d_in[4];
    const float* gamma = (const float*)d_in[5];
    const float* beta  = (const float*)d_in[6];
    const int*   tgt   = (const int*)d_in[7];
    float* out = (float*)d_out;

    float* ws = (float*)d_ws;
    const int TH = T * H;
    float* Z    = ws;               // TH
    float* HZ   = Z    + TH;
    float* u0   = HZ   + TH;
    float* D    = u0   + TH;
    float* SD   = D    + TH;
    float* S    = SD   + TH;
    float* c    = S    + TH;        // T
    float* Beta = c    + T;         // T*T

    k1<<<1032, 256, 0, stream>>>(h, U, a, Z, HZ, c, S);
    k2<<<1552, 256, 0, stream>>>(Z, W, b, HZ, c, u0, Beta);
    k3<<<T,     64, 0, stream>>>(u0, gamma, beta, tgt, S, D, SD);
    k4<<<T,   1024, 0, stream>>>(Beta, D, SD, u0, S, gamma, beta, out);
}

// Round 10
// 119.360 us; speedup vs baseline: 1.0700x; 1.0700x over previous
//
#include <hip/hip_runtime.h>

#define T 256
#define H 512
#define EPSF 1e-5f

__device__ __forceinline__ float block_sum(float v, float* s4) {
    for (int o = 32; o; o >>= 1) v += __shfl_xor(v, o);
    int w = threadIdx.x >> 6;
    __syncthreads();
    if ((threadIdx.x & 63) == 0) s4[w] = v;
    __syncthreads();
    return s4[0] + s4[1] + s4[2] + s4[3];
}

__device__ __forceinline__ float block_max(float v, float* s4) {
    for (int o = 32; o; o >>= 1) v = fmaxf(v, __shfl_xor(v, o));
    int w = threadIdx.x >> 6;
    __syncthreads();
    if ((threadIdx.x & 63) == 0) s4[w] = v;
    __syncthreads();
    return fmaxf(fmaxf(s4[0], s4[1]), fmaxf(s4[2], s4[3]));
}

// 1024-thread block sum (16 waves)
__device__ __forceinline__ float bsum16(float v, float* s16) {
    for (int o = 32; o; o >>= 1) v += __shfl_xor(v, o);
    int w = threadIdx.x >> 6;
    __syncthreads();
    if ((threadIdx.x & 63) == 0) s16[w] = v;
    __syncthreads();
    float r = 0.f;
    #pragma unroll
    for (int i = 0; i < 16; ++i) r += s16[i];
    return r;
}

// bid 0..7: S-scan (two-pass, 64 cols/block, wave = 64-t chunk).
// bid 8..519: Z=relu(h@U+a), HZ=h.*Z, c. Tile 2t x 128q, K-split-4 across waves.
__global__ __launch_bounds__(256) void k1(
        const float* __restrict__ h, const float* __restrict__ U,
        const float* __restrict__ a, float* __restrict__ Z,
        float* __restrict__ HZ, float* __restrict__ c, float* __restrict__ S) {
    int bid = blockIdx.x, tid = threadIdx.x;
    int lane = tid & 63, w = tid >> 6;
    if (bid < 8) {
        __shared__ float csum[4][64];
        int q = bid * 64 + lane;
        int tbase = w * 64;
        float s = 0.f;
        for (int j = 0; j < 64; j += 8) {
            float v[8];
            #pragma unroll
            for (int u = 0; u < 8; ++u) v[u] = h[(tbase + j + u) * H + q];
            #pragma unroll
            for (int u = 0; u < 8; ++u) s += v[u];
        }
        csum[w][lane] = s;
        __syncthreads();
        float acc = 0.f;
        #pragma unroll
        for (int w2 = 0; w2 < 3; ++w2) if (w2 < w) acc += csum[w2][lane];
        for (int j = 0; j < 64; j += 8) {
            float v[8];
            #pragma unroll
            for (int u = 0; u < 8; ++u) v[u] = h[(tbase + j + u) * H + q];
            #pragma unroll
            for (int u = 0; u < 8; ++u) { acc += v[u]; S[(tbase + j + u) * H + q] = acc; }
        }
        return;
    }
    int b = bid - 8;
    int t0 = (b >> 2) * 2, qt = b & 3;
    __shared__ __align__(16) float sh[1024];
    __shared__ float2 part[3][2][64];
    ((float4*)sh)[tid] = ((const float4*)(h + t0 * H))[tid];
    __syncthreads();

    if (qt == 0 && w < 2) {
        float s = 0.f;
        #pragma unroll
        for (int j = 0; j < 8; ++j) s += sh[w * 512 + lane + j * 64];
        for (int o = 32; o; o >>= 1) s += __shfl_xor(s, o);
        if (lane == 0) c[t0 + w] = s;
    }

    int qc = qt * 64 + lane;
    const float2* U2 = (const float2*)U;
    float2 acc0 = {0.f, 0.f}, acc1 = {0.f, 0.f};
    int kbeg = w * 128;
    for (int k0 = kbeg; k0 < kbeg + 128; k0 += 8) {
        float2 bv[8];
        #pragma unroll
        for (int u = 0; u < 8; ++u) bv[u] = U2[(k0 + u) * 256 + qc];
        float a0[8], a1[8];
        #pragma unroll
        for (int u = 0; u < 8; ++u) { a0[u] = sh[k0 + u]; a1[u] = sh[512 + k0 + u]; }
        #pragma unroll
        for (int u = 0; u < 8; ++u) {
            acc0.x += a0[u] * bv[u].x; acc0.y += a0[u] * bv[u].y;
            acc1.x += a1[u] * bv[u].x; acc1.y += a1[u] * bv[u].y;
        }
    }
    if (w) { part[w - 1][0][lane] = acc0; part[w - 1][1][lane] = acc1; }
    __syncthreads();
    if (w == 0) {
        #pragma unroll
        for (int p = 0; p < 3; ++p) {
            acc0.x += part[p][0][lane].x; acc0.y += part[p][0][lane].y;
            acc1.x += part[p][1][lane].x; acc1.y += part[p][1][lane].y;
        }
        float2 av = ((const float2*)a)[qc];
        float z0x = fmaxf(acc0.x + av.x, 0.f), z0y = fmaxf(acc0.y + av.y, 0.f);
        float z1x = fmaxf(acc1.x + av.x, 0.f), z1y = fmaxf(acc1.y + av.y, 0.f);
        float2 h0 = ((float2*)sh)[qc], h1 = ((float2*)sh)[256 + qc];
        ((float2*)Z)[t0 * 256 + qc]        = make_float2(z0x, z0y);
        ((float2*)Z)[(t0 + 1) * 256 + qc]  = make_float2(z1x, z1y);
        ((float2*)HZ)[t0 * 256 + qc]       = make_float2(h0.x * z0x, h0.y * z0y);
        ((float2*)HZ)[(t0 + 1) * 256 + qc] = make_float2(h1.x * z1x, h1.y * z1y);
    }
}

// bid 0..511: u0 = Z@W + b (tile 2t x 128q, K-split-4).
// bid 512..1039: Beta = tril(Z@HZ^T,-1)+c, compact triangular 8x8 tiles.
__global__ __launch_bounds__(256) void k2(
        const float* __restrict__ Z, const float* __restrict__ W,
        const float* __restrict__ bb, const float* __restrict__ HZ,
        const float* __restrict__ c, float* __restrict__ u0,
        float* __restrict__ Beta) {
    __shared__ __align__(16) float smem[2 * 8 * 516 + 256];
    int bid = blockIdx.x, tid = threadIdx.x;
    int lane = tid & 63, w = tid >> 6;
    if (bid < 512) {
        float* sh = smem;
        float2* part = (float2*)(smem + 1024);
        int t0 = (bid >> 2) * 2, qt = bid & 3;
        ((float4*)sh)[tid] = ((const float4*)(Z + t0 * H))[tid];
        __syncthreads();
        int qc = qt * 64 + lane;
        const float2* W2 = (const float2*)W;
        float2 acc0 = {0.f, 0.f}, acc1 = {0.f, 0.f};
        int kbeg = w * 128;
        for (int k0 = kbeg; k0 < kbeg + 128; k0 += 8) {
            float2 bv[8];
            #pragma unroll
            for (int u = 0; u < 8; ++u) bv[u] = W2[(k0 + u) * 256 + qc];
            float a0[8], a1[8];
            #pragma unroll
            for (int u = 0; u < 8; ++u) { a0[u] = sh[k0 + u]; a1[u] = sh[512 + k0 + u]; }
            #pragma unroll
            for (int u = 0; u < 8; ++u) {
                acc0.x += a0[u] * bv[u].x; acc0.y += a0[u] * bv[u].y;
                acc1.x += a1[u] * bv[u].x; acc1.y += a1[u] * bv[u].y;
            }
        }
        if (w) { part[((w - 1) * 2 + 0) * 64 + lane] = acc0; part[((w - 1) * 2 + 1) * 64 + lane] = acc1; }
        __syncthreads();
        if (w == 0) {
            #pragma unroll
            for (int p = 0; p < 3; ++p) {
                float2 p0 = part[(p * 2 + 0) * 64 + lane];
                float2 p1 = part[(p * 2 + 1) * 64 + lane];
                acc0.x += p0.x; acc0.y += p0.y;
                acc1.x += p1.x; acc1.y += p1.y;
            }
            float2 bv = ((const float2*)bb)[qc];
            ((float2*)u0)[t0 * 256 + qc]       = make_float2(acc0.x + bv.x, acc0.y + bv.y);
            ((float2*)u0)[(t0 + 1) * 256 + qc] = make_float2(acc1.x + bv.x, acc1.y + bv.y);
        }
    } else {
        int e = bid - 512;                         // 0..527 compact triangular
        int ti = (int)((sqrtf(8.f * (float)e + 1.f) - 1.f) * 0.5f);
        while ((ti + 1) * (ti + 2) / 2 <= e) ++ti;
        while (ti * (ti + 1) / 2 > e) --ti;
        int ii = e - ti * (ti + 1) / 2;
        int t0 = ti * 8, i0 = ii * 8;
        float* Zs = smem;                 // [8][516]
        float* Hs = smem + 8 * 516;       // [8][516]
        float* red = smem + 2 * 8 * 516;  // [4][64]
        #pragma unroll
        for (int j = 0; j < 4; ++j) {
            int idx = tid + j * 256;
            int row = idx >> 7, col4 = idx & 127;
            float4 v = ((const float4*)(Z + (t0 + row) * H))[col4];
            *(float4*)&Zs[row * 516 + col4 * 4] = v;
            float4 g = ((const float4*)(HZ + (i0 + row) * H))[col4];
            *(float4*)&Hs[row * 516 + col4 * 4] = g;
        }
        __syncthreads();
        int ks = tid >> 6, r = (tid >> 3) & 7, ci = tid & 7;
        float acc = 0.f;
        int kb = ks * 128;
        #pragma unroll 4
        for (int k0 = kb; k0 < kb + 128; k0 += 8) {
            float4 z0 = *(float4*)&Zs[r * 516 + k0];
            float4 z1 = *(float4*)&Zs[r * 516 + k0 + 4];
            float4 h0 = *(float4*)&Hs[ci * 516 + k0];
            float4 h1 = *(float4*)&Hs[ci * 516 + k0 + 4];
            acc += z0.x * h0.x + z0.y * h0.y + z0.z * h0.z + z0.w * h0.w
                 + z1.x * h1.x + z1.y * h1.y + z1.z * h1.z + z1.w * h1.w;
        }
        red[ks * 64 + r * 8 + ci] = acc;
        __syncthreads();
        if (tid < 64) {
            int r2 = tid >> 3, c2 = tid & 7;
            float v = red[tid] + red[64 + tid] + red[128 + tid] + red[192 + tid];
            int t = t0 + r2, i = i0 + c2;
            Beta[t * 256 + i] = (i < t) ? v + c[i] : 0.f;
        }
    }
}

// Per-row t: y=LN(u0), g=softmax(y)-onehot, D=LN-backward(g), SD=S.*D
__global__ __launch_bounds__(256) void k3(
        const float* __restrict__ u0, const float* __restrict__ gamma,
        const float* __restrict__ beta, const int* __restrict__ targets,
        const float* __restrict__ S, float* __restrict__ D, float* __restrict__ SD) {
    __shared__ float s4[4];
    int t = blockIdx.x, tid = threadIdx.x;
    float2 uv = ((const float2*)u0)[t * 256 + tid];
    float2 gv = ((const float2*)gamma)[tid];
    float2 bv = ((const float2*)beta)[tid];

    float m = block_sum(uv.x + uv.y, s4) * (1.f / H);
    float d0 = uv.x - m, d1 = uv.y - m;
    float var = block_sum(d0 * d0 + d1 * d1, s4) * (1.f / H);
    float s = rsqrtf(var + EPSF);
    float xh0 = d0 * s, xh1 = d1 * s;
    float y0 = xh0 * gv.x + bv.x;
    float y1 = xh1 * gv.y + bv.y;

    float ymax = block_max(fmaxf(y0, y1), s4);
    float e0 = __expf(y0 - ymax), e1 = __expf(y1 - ymax);
    float Zs = block_sum(e0 + e1, s4);
    float invZ = 1.f / Zs;
    int tgt = targets[t];
    float g0 = e0 * invZ - (2 * tid == tgt ? 1.f : 0.f);
    float g1 = e1 * invZ - (2 * tid + 1 == tgt ? 1.f : 0.f);
    float gy0 = g0 * gv.x, gy1 = g1 * gv.y;

    float mgy = block_sum(gy0 + gy1, s4) * (1.f / H);
    float mgx = block_sum(gy0 * xh0 + gy1 * xh1, s4) * (1.f / H);

    float dd0 = s * (gy0 - mgy - xh0 * mgx);
    float dd1 = s * (gy1 - mgy - xh1 * mgx);
    float2 sv = ((const float2*)S)[t * 256 + tid];
    ((float2*)D)[t * 256 + tid]  = make_float2(dd0, dd1);
    ((float2*)SD)[t * 256 + tid] = make_float2(sv.x * dd0, sv.y * dd1);
}

// One block (1024 thr) per FOUR rows t0..t0+3: each dv/sv load feeds 4 rows
// (16 FMA / 16 B vs 4 before) -> 4x less D/SD re-read traffic (134 -> 33 MB).
// Beta zero-padding (Beta[t][i]=0 for i>=t) makes the shared k-range correct.
__global__ __launch_bounds__(1024) void k4(
        const float* __restrict__ Beta, const float* __restrict__ D,
        const float* __restrict__ SD, const float* __restrict__ u0,
        const float* __restrict__ S, const float* __restrict__ gamma,
        const float* __restrict__ beta, float* __restrict__ out) {
    __shared__ float Brow[4][256];
    __shared__ float r1[4][512];
    __shared__ float r2[4][512];
    __shared__ float s16[16];
    int t0 = blockIdx.x * 4, tid = threadIdx.x;
    {
        int r = tid >> 8, ci = tid & 255;
        Brow[r][ci] = Beta[(t0 + r) * 256 + ci];
    }
    __syncthreads();

    int ig = tid >> 8, qc = tid & 255;
    int ibeg = ig * 64;
    int ie = min(256, (t0 + 3 + 7) & ~7);     // max row's tile-padded bound
    int iend = min(ie, ibeg + 64);
    float2 a1[4], a2[4];
    #pragma unroll
    for (int r = 0; r < 4; ++r) { a1[r] = make_float2(0.f, 0.f); a2[r] = make_float2(0.f, 0.f); }
    const float2* D2 = (const float2*)D;
    const float2* SD2 = (const float2*)SD;
    for (int k0 = ibeg; k0 < iend; k0 += 8) {
        float2 dv[8], sv[8];
        #pragma unroll
        for (int u = 0; u < 8; ++u) {
            dv[u] = D2[(k0 + u) * 256 + qc];
            sv[u] = SD2[(k0 + u) * 256 + qc];
        }
        #pragma unroll
        for (int u = 0; u < 8; ++u) {
            #pragma unroll
            for (int r = 0; r < 4; ++r) {
                float bw = Brow[r][k0 + u];
                a1[r].x += bw * dv[u].x; a1[r].y += bw * dv[u].y;
                a2[r].x += bw * sv[u].x; a2[r].y += bw * sv[u].y;
            }
        }
    }

    #pragma unroll
    for (int r = 0; r < 4; ++r) {
        // WAR on r1/r2 vs previous row's reads is covered by bsum16's barriers.
        r1[ig][2 * qc] = a1[r].x; r1[ig][2 * qc + 1] = a1[r].y;
        r2[ig][2 * qc] = a2[r].x; r2[ig][2 * qc + 1] = a2[r].y;
        __syncthreads();
        float p = 0.f;
        int t = t0 + r;
        if (tid < 512) {
            float A1 = r1[0][tid] + r1[1][tid] + r1[2][tid] + r1[3][tid];
            float A2 = r2[0][tid] + r2[1][tid] + r2[2][tid] + r2[3][tid];
            p = u0[t * H + tid] - S[t * H + tid] * A1 + A2;
        }
        float m = bsum16(p, s16) * (1.f / H);
        float d = (tid < 512) ? p - m : 0.f;
        float var = bsum16(d * d, s16) * (1.f / H);
        float s = rsqrtf(var + EPSF);
        if (tid < 512)
            out[t * H + tid] = d * s * gamma[tid] + beta[tid];
        __syncthreads();
    }
}

extern "C" void kernel_launch(void* const* d_in, const int* in_sizes, int n_in,
                              void* d_out, int out_size, void* d_ws, size_t ws_size,
                              hipStream_t stream) {
    const float* h     = (const float*)d_in[0];
    const float* U     = (const float*)d_in[1];
    const float* W     = (const float*)d_in[2];
    const float* a     = (const float*)d_in[3];
    const float* b     = (const float*)d_in[4];
    const float* gamma = (const float*)d_in[5];
    const float* beta  = (const float*)d_in[6];
    const int*   tgt   = (const int*)d_in[7];
    float* out = (float*)d_out;

    float* ws = (float*)d_ws;
    const int TH = T * H;
    float* Z    = ws;               // TH
    float* HZ   = Z    + TH;
    float* u0   = HZ   + TH;
    float* D    = u0   + TH;
    float* SD   = D    + TH;
    float* S    = SD   + TH;
    float* c    = S    + TH;        // T
    float* Beta = c    + T;         // T*T

    k1<<<520,    256, 0, stream>>>(h, U, a, Z, HZ, c, S);
    k2<<<1040,   256, 0, stream>>>(Z, W, b, HZ, c, u0, Beta);
    k3<<<T,      256, 0, stream>>>(u0, gamma, beta, tgt, S, D, SD);
    k4<<<T / 4, 1024, 0, stream>>>(Beta, D, SD, u0, S, gamma, beta, out);
}

// Round 11
// 104.280 us; speedup vs baseline: 1.2248x; 1.1446x over previous
//
#include <hip/hip_runtime.h>

#define T 256
#define H 512
#define EPSF 1e-5f

__device__ __forceinline__ float block_sum(float v, float* s4) {
    for (int o = 32; o; o >>= 1) v += __shfl_xor(v, o);
    int w = threadIdx.x >> 6;
    __syncthreads();
    if ((threadIdx.x & 63) == 0) s4[w] = v;
    __syncthreads();
    return s4[0] + s4[1] + s4[2] + s4[3];
}

__device__ __forceinline__ float block_max(float v, float* s4) {
    for (int o = 32; o; o >>= 1) v = fmaxf(v, __shfl_xor(v, o));
    int w = threadIdx.x >> 6;
    __syncthreads();
    if ((threadIdx.x & 63) == 0) s4[w] = v;
    __syncthreads();
    return fmaxf(fmaxf(s4[0], s4[1]), fmaxf(s4[2], s4[3]));
}

// bid 0..7: S-scan (two-pass, 64 cols/block, wave = 64-t chunk).
// bid 8..519: Z=relu(h@U+a), HZ=h.*Z, c. Tile 2t x 128q, K-split-4 across waves.
__global__ __launch_bounds__(256) void k1(
        const float* __restrict__ h, const float* __restrict__ U,
        const float* __restrict__ a, float* __restrict__ Z,
        float* __restrict__ HZ, float* __restrict__ c, float* __restrict__ S) {
    int bid = blockIdx.x, tid = threadIdx.x;
    int lane = tid & 63, w = tid >> 6;
    if (bid < 8) {
        __shared__ float csum[4][64];
        int q = bid * 64 + lane;
        int tbase = w * 64;
        float s = 0.f;
        for (int j = 0; j < 64; j += 8) {
            float v[8];
            #pragma unroll
            for (int u = 0; u < 8; ++u) v[u] = h[(tbase + j + u) * H + q];
            #pragma unroll
            for (int u = 0; u < 8; ++u) s += v[u];
        }
        csum[w][lane] = s;
        __syncthreads();
        float acc = 0.f;
        #pragma unroll
        for (int w2 = 0; w2 < 3; ++w2) if (w2 < w) acc += csum[w2][lane];
        for (int j = 0; j < 64; j += 8) {
            float v[8];
            #pragma unroll
            for (int u = 0; u < 8; ++u) v[u] = h[(tbase + j + u) * H + q];
            #pragma unroll
            for (int u = 0; u < 8; ++u) { acc += v[u]; S[(tbase + j + u) * H + q] = acc; }
        }
        return;
    }
    int b = bid - 8;
    int t0 = (b >> 2) * 2, qt = b & 3;
    __shared__ __align__(16) float sh[1024];
    __shared__ float2 part[3][2][64];
    ((float4*)sh)[tid] = ((const float4*)(h + t0 * H))[tid];
    __syncthreads();

    if (qt == 0 && w < 2) {
        float s = 0.f;
        #pragma unroll
        for (int j = 0; j < 8; ++j) s += sh[w * 512 + lane + j * 64];
        for (int o = 32; o; o >>= 1) s += __shfl_xor(s, o);
        if (lane == 0) c[t0 + w] = s;
    }

    int qc = qt * 64 + lane;
    const float2* U2 = (const float2*)U;
    float2 acc0 = {0.f, 0.f}, acc1 = {0.f, 0.f};
    int kbeg = w * 128;
    for (int k0 = kbeg; k0 < kbeg + 128; k0 += 8) {
        float2 bv[8];
        #pragma unroll
        for (int u = 0; u < 8; ++u) bv[u] = U2[(k0 + u) * 256 + qc];
        float a0[8], a1[8];
        #pragma unroll
        for (int u = 0; u < 8; ++u) { a0[u] = sh[k0 + u]; a1[u] = sh[512 + k0 + u]; }
        #pragma unroll
        for (int u = 0; u < 8; ++u) {
            acc0.x += a0[u] * bv[u].x; acc0.y += a0[u] * bv[u].y;
            acc1.x += a1[u] * bv[u].x; acc1.y += a1[u] * bv[u].y;
        }
    }
    if (w) { part[w - 1][0][lane] = acc0; part[w - 1][1][lane] = acc1; }
    __syncthreads();
    if (w == 0) {
        #pragma unroll
        for (int p = 0; p < 3; ++p) {
            acc0.x += part[p][0][lane].x; acc0.y += part[p][0][lane].y;
            acc1.x += part[p][1][lane].x; acc1.y += part[p][1][lane].y;
        }
        float2 av = ((const float2*)a)[qc];
        float z0x = fmaxf(acc0.x + av.x, 0.f), z0y = fmaxf(acc0.y + av.y, 0.f);
        float z1x = fmaxf(acc1.x + av.x, 0.f), z1y = fmaxf(acc1.y + av.y, 0.f);
        float2 h0 = ((float2*)sh)[qc], h1 = ((float2*)sh)[256 + qc];
        ((float2*)Z)[t0 * 256 + qc]        = make_float2(z0x, z0y);
        ((float2*)Z)[(t0 + 1) * 256 + qc]  = make_float2(z1x, z1y);
        ((float2*)HZ)[t0 * 256 + qc]       = make_float2(h0.x * z0x, h0.y * z0y);
        ((float2*)HZ)[(t0 + 1) * 256 + qc] = make_float2(h1.x * z1x, h1.y * z1y);
    }
}

// bid 0..511: u0 = Z@W + b (tile 2t x 128q, K-split-4).
// bid 512..1039: Beta = tril(Z@HZ^T,-1)+c, compact triangular 8x8 tiles.
__global__ __launch_bounds__(256) void k2(
        const float* __restrict__ Z, const float* __restrict__ W,
        const float* __restrict__ bb, const float* __restrict__ HZ,
        const float* __restrict__ c, float* __restrict__ u0,
        float* __restrict__ Beta) {
    __shared__ __align__(16) float smem[2 * 8 * 516 + 256];
    int bid = blockIdx.x, tid = threadIdx.x;
    int lane = tid & 63, w = tid >> 6;
    if (bid < 512) {
        float* sh = smem;
        float2* part = (float2*)(smem + 1024);
        int t0 = (bid >> 2) * 2, qt = bid & 3;
        ((float4*)sh)[tid] = ((const float4*)(Z + t0 * H))[tid];
        __syncthreads();
        int qc = qt * 64 + lane;
        const float2* W2 = (const float2*)W;
        float2 acc0 = {0.f, 0.f}, acc1 = {0.f, 0.f};
        int kbeg = w * 128;
        for (int k0 = kbeg; k0 < kbeg + 128; k0 += 8) {
            float2 bv[8];
            #pragma unroll
            for (int u = 0; u < 8; ++u) bv[u] = W2[(k0 + u) * 256 + qc];
            float a0[8], a1[8];
            #pragma unroll
            for (int u = 0; u < 8; ++u) { a0[u] = sh[k0 + u]; a1[u] = sh[512 + k0 + u]; }
            #pragma unroll
            for (int u = 0; u < 8; ++u) {
                acc0.x += a0[u] * bv[u].x; acc0.y += a0[u] * bv[u].y;
                acc1.x += a1[u] * bv[u].x; acc1.y += a1[u] * bv[u].y;
            }
        }
        if (w) { part[((w - 1) * 2 + 0) * 64 + lane] = acc0; part[((w - 1) * 2 + 1) * 64 + lane] = acc1; }
        __syncthreads();
        if (w == 0) {
            #pragma unroll
            for (int p = 0; p < 3; ++p) {
                float2 p0 = part[(p * 2 + 0) * 64 + lane];
                float2 p1 = part[(p * 2 + 1) * 64 + lane];
                acc0.x += p0.x; acc0.y += p0.y;
                acc1.x += p1.x; acc1.y += p1.y;
            }
            float2 bv = ((const float2*)bb)[qc];
            ((float2*)u0)[t0 * 256 + qc]       = make_float2(acc0.x + bv.x, acc0.y + bv.y);
            ((float2*)u0)[(t0 + 1) * 256 + qc] = make_float2(acc1.x + bv.x, acc1.y + bv.y);
        }
    } else {
        int e = bid - 512;                         // 0..527 compact triangular
        int ti = (int)((sqrtf(8.f * (float)e + 1.f) - 1.f) * 0.5f);
        while ((ti + 1) * (ti + 2) / 2 <= e) ++ti;
        while (ti * (ti + 1) / 2 > e) --ti;
        int ii = e - ti * (ti + 1) / 2;
        int t0 = ti * 8, i0 = ii * 8;
        float* Zs = smem;                 // [8][516]
        float* Hs = smem + 8 * 516;       // [8][516]
        float* red = smem + 2 * 8 * 516;  // [4][64]
        #pragma unroll
        for (int j = 0; j < 4; ++j) {
            int idx = tid + j * 256;
            int row = idx >> 7, col4 = idx & 127;
            float4 v = ((const float4*)(Z + (t0 + row) * H))[col4];
            *(float4*)&Zs[row * 516 + col4 * 4] = v;
            float4 g = ((const float4*)(HZ + (i0 + row) * H))[col4];
            *(float4*)&Hs[row * 516 + col4 * 4] = g;
        }
        __syncthreads();
        int ks = tid >> 6, r = (tid >> 3) & 7, ci = tid & 7;
        float acc = 0.f;
        int kb = ks * 128;
        #pragma unroll 4
        for (int k0 = kb; k0 < kb + 128; k0 += 8) {
            float4 z0 = *(float4*)&Zs[r * 516 + k0];
            float4 z1 = *(float4*)&Zs[r * 516 + k0 + 4];
            float4 h0 = *(float4*)&Hs[ci * 516 + k0];
            float4 h1 = *(float4*)&Hs[ci * 516 + k0 + 4];
            acc += z0.x * h0.x + z0.y * h0.y + z0.z * h0.z + z0.w * h0.w
                 + z1.x * h1.x + z1.y * h1.y + z1.z * h1.z + z1.w * h1.w;
        }
        red[ks * 64 + r * 8 + ci] = acc;
        __syncthreads();
        if (tid < 64) {
            int r2 = tid >> 3, c2 = tid & 7;
            float v = red[tid] + red[64 + tid] + red[128 + tid] + red[192 + tid];
            int t = t0 + r2, i = i0 + c2;
            Beta[t * 256 + i] = (i < t) ? v + c[i] : 0.f;
        }
    }
}

// Per-row t: y=LN(u0), g=softmax(y)-onehot, D=LN-backward(g), SD=S.*D
__global__ __launch_bounds__(256) void k3(
        const float* __restrict__ u0, const float* __restrict__ gamma,
        const float* __restrict__ beta, const int* __restrict__ targets,
        const float* __restrict__ S, float* __restrict__ D, float* __restrict__ SD) {
    __shared__ float s4[4];
    int t = blockIdx.x, tid = threadIdx.x;
    float2 uv = ((const float2*)u0)[t * 256 + tid];
    float2 gv = ((const float2*)gamma)[tid];
    float2 bv = ((const float2*)beta)[tid];

    float m = block_sum(uv.x + uv.y, s4) * (1.f / H);
    float d0 = uv.x - m, d1 = uv.y - m;
    float var = block_sum(d0 * d0 + d1 * d1, s4) * (1.f / H);
    float s = rsqrtf(var + EPSF);
    float xh0 = d0 * s, xh1 = d1 * s;
    float y0 = xh0 * gv.x + bv.x;
    float y1 = xh1 * gv.y + bv.y;

    float ymax = block_max(fmaxf(y0, y1), s4);
    float e0 = __expf(y0 - ymax), e1 = __expf(y1 - ymax);
    float Zs = block_sum(e0 + e1, s4);
    float invZ = 1.f / Zs;
    int tgt = targets[t];
    float g0 = e0 * invZ - (2 * tid == tgt ? 1.f : 0.f);
    float g1 = e1 * invZ - (2 * tid + 1 == tgt ? 1.f : 0.f);
    float gy0 = g0 * gv.x, gy1 = g1 * gv.y;

    float mgy = block_sum(gy0 + gy1, s4) * (1.f / H);
    float mgx = block_sum(gy0 * xh0 + gy1 * xh1, s4) * (1.f / H);

    float dd0 = s * (gy0 - mgy - xh0 * mgx);
    float dd1 = s * (gy1 - mgy - xh1 * mgx);
    float2 sv = ((const float2*)S)[t * 256 + tid];
    ((float2*)D)[t * 256 + tid]  = make_float2(dd0, dd1);
    ((float2*)SD)[t * 256 + tid] = make_float2(sv.x * dd0, sv.y * dd1);
}

// k4a: pre = u0 - S.*(Beta@D) + Beta@SD, col-split GEMM.
// 256 blocks: (row-group R0=8*(bid>>3), col-group g=bid&7 -> 32 float2 cols).
// Each D/SD load feeds 8 rows -> D/SD traffic 134 MB -> ~17 MB, full CU coverage.
// Beta's zero-padded diagonal tiles make the uniform k-range [0, R0+8) exact.
__global__ __launch_bounds__(256) void k4a(
        const float* __restrict__ Beta, const float* __restrict__ D,
        const float* __restrict__ SD, const float* __restrict__ u0,
        const float* __restrict__ S, float* __restrict__ pre) {
    __shared__ float Brow[8][256];      // 8 KB
    __shared__ float2 red1[8][8][32];   // 16 KB
    __shared__ float2 red2[8][8][32];   // 16 KB
    int bid = blockIdx.x, tid = threadIdx.x;
    int R0 = (bid >> 3) * 8;
    int g  = bid & 7;
    #pragma unroll
    for (int j = 0; j < 8; ++j) {
        int idx = tid + j * 256;
        int r = idx >> 8, ci = idx & 255;
        Brow[r][ci] = Beta[(R0 + r) * 256 + ci];
    }
    __syncthreads();

    int ks = tid >> 5, cc = tid & 31;
    int qc = g * 32 + cc;
    int kend = R0 + 8;
    float2 a1[8], a2[8];
    #pragma unroll
    for (int r = 0; r < 8; ++r) { a1[r] = make_float2(0.f, 0.f); a2[r] = make_float2(0.f, 0.f); }
    const float2* D2 = (const float2*)D;
    const float2* SD2 = (const float2*)SD;
    for (int i0 = ks * 8; i0 < kend; i0 += 64) {
        float2 dv[8], sv[8];
        #pragma unroll
        for (int u = 0; u < 8; ++u) {
            dv[u] = D2[(i0 + u) * 256 + qc];
            sv[u] = SD2[(i0 + u) * 256 + qc];
        }
        #pragma unroll
        for (int u = 0; u < 8; ++u) {
            #pragma unroll
            for (int r = 0; r < 8; ++r) {
                float bw = Brow[r][i0 + u];         // wave-broadcast LDS read
                a1[r].x += bw * dv[u].x; a1[r].y += bw * dv[u].y;
                a2[r].x += bw * sv[u].x; a2[r].y += bw * sv[u].y;
            }
        }
    }
    #pragma unroll
    for (int r = 0; r < 8; ++r) { red1[ks][r][cc] = a1[r]; red2[ks][r][cc] = a2[r]; }
    __syncthreads();

    {
        int r = tid >> 5, c = tid & 31;
        float2 A1 = make_float2(0.f, 0.f), A2 = make_float2(0.f, 0.f);
        #pragma unroll
        for (int p = 0; p < 8; ++p) {
            float2 v1 = red1[p][r][c], v2 = red2[p][r][c];
            A1.x += v1.x; A1.y += v1.y;
            A2.x += v2.x; A2.y += v2.y;
        }
        int t = R0 + r;
        int col = g * 32 + c;
        float2 uv = ((const float2*)u0)[t * 256 + col];
        float2 sv = ((const float2*)S)[t * 256 + col];
        float2 p;
        p.x = uv.x - sv.x * A1.x + A2.x;
        p.y = uv.y - sv.y * A1.y + A2.y;
        ((float2*)pre)[t * 256 + col] = p;
    }
}

// k4b: out = LN(pre) per row, 256 thr/row.
__global__ __launch_bounds__(256) void k4b(
        const float* __restrict__ pre, const float* __restrict__ gamma,
        const float* __restrict__ beta, float* __restrict__ out) {
    __shared__ float s4[4];
    int t = blockIdx.x, tid = threadIdx.x;
    float2 pv = ((const float2*)pre)[t * 256 + tid];
    float m = block_sum(pv.x + pv.y, s4) * (1.f / H);
    float d0 = pv.x - m, d1 = pv.y - m;
    float var = block_sum(d0 * d0 + d1 * d1, s4) * (1.f / H);
    float s = rsqrtf(var + EPSF);
    float2 gv = ((const float2*)gamma)[tid];
    float2 bv = ((const float2*)beta)[tid];
    ((float2*)out)[t * 256 + tid] =
        make_float2(d0 * s * gv.x + bv.x, d1 * s * gv.y + bv.y);
}

extern "C" void kernel_launch(void* const* d_in, const int* in_sizes, int n_in,
                              void* d_out, int out_size, void* d_ws, size_t ws_size,
                              hipStream_t stream) {
    const float* h     = (const float*)d_in[0];
    const float* U     = (const float*)d_in[1];
    const float* W     = (const float*)d_in[2];
    const float* a     = (const float*)d_in[3];
    const float* b     = (const float*)d_in[4];
    const float* gamma = (const float*)d_in[5];
    const float* beta  = (const float*)d_in[6];
    const int*   tgt   = (const int*)d_in[7];
    float* out = (float*)d_out;

    float* ws = (float*)d_ws;
    const int TH = T * H;
    float* Z    = ws;               // TH
    float* HZ   = Z    + TH;
    float* u0   = HZ   + TH;
    float* D    = u0   + TH;
    float* SD   = D    + TH;
    float* S    = SD   + TH;
    float* c    = S    + TH;        // T
    float* Beta = c    + T;         // T*T
    float* pre  = Beta + T * T;     // TH

    k1<<<520,  256, 0, stream>>>(h, U, a, Z, HZ, c, S);
    k2<<<1040, 256, 0, stream>>>(Z, W, b, HZ, c, u0, Beta);
    k3<<<T,    256, 0, stream>>>(u0, gamma, beta, tgt, S, D, SD);
    k4a<<<256, 256, 0, stream>>>(Beta, D, SD, u0, S, pre);
    k4b<<<T,   256, 0, stream>>>(pre, gamma, beta, out);
}

// Round 13
// 100.499 us; speedup vs baseline: 1.2709x; 1.0376x over previous
//
#include <hip/hip_runtime.h>

#define T 256
#define H 512
#define EPSF 1e-5f

__device__ __forceinline__ float block_sum(float v, float* s4) {
    for (int o = 32; o; o >>= 1) v += __shfl_xor(v, o);
    int w = threadIdx.x >> 6;
    __syncthreads();
    if ((threadIdx.x & 63) == 0) s4[w] = v;
    __syncthreads();
    return s4[0] + s4[1] + s4[2] + s4[3];
}

__device__ __forceinline__ float block_max(float v, float* s4) {
    for (int o = 32; o; o >>= 1) v = fmaxf(v, __shfl_xor(v, o));
    int w = threadIdx.x >> 6;
    __syncthreads();
    if ((threadIdx.x & 63) == 0) s4[w] = v;
    __syncthreads();
    return fmaxf(fmaxf(s4[0], s4[1]), fmaxf(s4[2], s4[3]));
}

// bid 0..7: S-scan (two-pass, 64 cols/block, wave = 64-t chunk).
// bid 8..263: Z=relu(h@U+a), HZ=h.*Z, c. Tile 4t x 128q, K-split-4 across waves.
// 4-row tiles halve U-panel re-read traffic (128 -> 64 MB) at 256 GEMM blocks.
__global__ __launch_bounds__(256) void k1(
        const float* __restrict__ h, const float* __restrict__ U,
        const float* __restrict__ a, float* __restrict__ Z,
        float* __restrict__ HZ, float* __restrict__ c, float* __restrict__ S) {
    int bid = blockIdx.x, tid = threadIdx.x;
    int lane = tid & 63, w = tid >> 6;
    if (bid < 8) {
        __shared__ float csum[4][64];
        int q = bid * 64 + lane;
        int tbase = w * 64;
        float s = 0.f;
        for (int j = 0; j < 64; j += 8) {
            float v[8];
            #pragma unroll
            for (int u = 0; u < 8; ++u) v[u] = h[(tbase + j + u) * H + q];
            #pragma unroll
            for (int u = 0; u < 8; ++u) s += v[u];
        }
        csum[w][lane] = s;
        __syncthreads();
        float acc = 0.f;
        #pragma unroll
        for (int w2 = 0; w2 < 3; ++w2) if (w2 < w) acc += csum[w2][lane];
        for (int j = 0; j < 64; j += 8) {
            float v[8];
            #pragma unroll
            for (int u = 0; u < 8; ++u) v[u] = h[(tbase + j + u) * H + q];
            #pragma unroll
            for (int u = 0; u < 8; ++u) { acc += v[u]; S[(tbase + j + u) * H + q] = acc; }
        }
        return;
    }
    int b = bid - 8;                    // 0..255
    int t0 = (b >> 2) * 4, qt = b & 3;
    __shared__ __align__(16) float sh[2048];     // 4 rows x 512
    __shared__ float2 part[3][4][64];
    ((float4*)sh)[tid]       = ((const float4*)(h + t0 * H))[tid];
    ((float4*)sh)[tid + 256] = ((const float4*)(h + t0 * H))[tid + 256];
    __syncthreads();

    if (qt == 0) {                      // c: wave w sums its own row w
        float s = 0.f;
        #pragma unroll
        for (int j = 0; j < 8; ++j) s += sh[w * 512 + lane + j * 64];
        for (int o = 32; o; o >>= 1) s += __shfl_xor(s, o);
        if (lane == 0) c[t0 + w] = s;
    }

    int qc = qt * 64 + lane;
    const float2* U2 = (const float2*)U;
    float2 acc[4];
    #pragma unroll
    for (int r = 0; r < 4; ++r) acc[r] = make_float2(0.f, 0.f);
    int kbeg = w * 128;
    for (int k0 = kbeg; k0 < kbeg + 128; k0 += 8) {
        float2 bv[8];
        #pragma unroll
        for (int u = 0; u < 8; ++u) bv[u] = U2[(k0 + u) * 256 + qc];
        float av[4][8];
        #pragma unroll
        for (int r = 0; r < 4; ++r)
            #pragma unroll
            for (int u = 0; u < 8; ++u) av[r][u] = sh[r * 512 + k0 + u];
        #pragma unroll
        for (int u = 0; u < 8; ++u)
            #pragma unroll
            for (int r = 0; r < 4; ++r) {
                acc[r].x += av[r][u] * bv[u].x;
                acc[r].y += av[r][u] * bv[u].y;
            }
    }
    if (w) {
        #pragma unroll
        for (int r = 0; r < 4; ++r) part[w - 1][r][lane] = acc[r];
    }
    __syncthreads();
    if (w == 0) {
        #pragma unroll
        for (int p = 0; p < 3; ++p)
            #pragma unroll
            for (int r = 0; r < 4; ++r) {
                acc[r].x += part[p][r][lane].x;
                acc[r].y += part[p][r][lane].y;
            }
        float2 av2 = ((const float2*)a)[qc];
        #pragma unroll
        for (int r = 0; r < 4; ++r) {
            float zx = fmaxf(acc[r].x + av2.x, 0.f);
            float zy = fmaxf(acc[r].y + av2.y, 0.f);
            float2 hv = ((float2*)sh)[r * 256 + qc];
            ((float2*)Z)[(t0 + r) * 256 + qc]  = make_float2(zx, zy);
            ((float2*)HZ)[(t0 + r) * 256 + qc] = make_float2(hv.x * zx, hv.y * zy);
        }
    }
}

// bid 0..255: u0 = Z@W + b (tile 4t x 128q, K-split-4).
// bid 256..783: Beta = tril(Z@HZ^T,-1)+c, compact triangular 8x8 tiles.
__global__ __launch_bounds__(256) void k2(
        const float* __restrict__ Z, const float* __restrict__ W,
        const float* __restrict__ bb, const float* __restrict__ HZ,
        const float* __restrict__ c, float* __restrict__ u0,
        float* __restrict__ Beta) {
    __shared__ __align__(16) float smem[2 * 8 * 516 + 256];
    int bid = blockIdx.x, tid = threadIdx.x;
    int lane = tid & 63, w = tid >> 6;
    if (bid < 256) {
        float* sh = smem;                         // 2048 floats: 4 rows x 512
        float2* part = (float2*)(smem + 2048);    // [3][4][64] float2
        int t0 = (bid >> 2) * 4, qt = bid & 3;
        ((float4*)sh)[tid]       = ((const float4*)(Z + t0 * H))[tid];
        ((float4*)sh)[tid + 256] = ((const float4*)(Z + t0 * H))[tid + 256];
        __syncthreads();
        int qc = qt * 64 + lane;
        const float2* W2 = (const float2*)W;
        float2 acc[4];
        #pragma unroll
        for (int r = 0; r < 4; ++r) acc[r] = make_float2(0.f, 0.f);
        int kbeg = w * 128;
        for (int k0 = kbeg; k0 < kbeg + 128; k0 += 8) {
            float2 bv[8];
            #pragma unroll
            for (int u = 0; u < 8; ++u) bv[u] = W2[(k0 + u) * 256 + qc];
            float av[4][8];
            #pragma unroll
            for (int r = 0; r < 4; ++r)
                #pragma unroll
                for (int u = 0; u < 8; ++u) av[r][u] = sh[r * 512 + k0 + u];
            #pragma unroll
            for (int u = 0; u < 8; ++u)
                #pragma unroll
                for (int r = 0; r < 4; ++r) {
                    acc[r].x += av[r][u] * bv[u].x;
                    acc[r].y += av[r][u] * bv[u].y;
                }
        }
        if (w) {
            #pragma unroll
            for (int r = 0; r < 4; ++r) part[((w - 1) * 4 + r) * 64 + lane] = acc[r];
        }
        __syncthreads();
        if (w == 0) {
            #pragma unroll
            for (int p = 0; p < 3; ++p)
                #pragma unroll
                for (int r = 0; r < 4; ++r) {
                    float2 pv = part[(p * 4 + r) * 64 + lane];
                    acc[r].x += pv.x; acc[r].y += pv.y;
                }
            float2 bv = ((const float2*)bb)[qc];
            #pragma unroll
            for (int r = 0; r < 4; ++r)
                ((float2*)u0)[(t0 + r) * 256 + qc] =
                    make_float2(acc[r].x + bv.x, acc[r].y + bv.y);
        }
    } else {
        int e = bid - 256;                         // 0..527 compact triangular
        int ti = (int)((sqrtf(8.f * (float)e + 1.f) - 1.f) * 0.5f);
        while ((ti + 1) * (ti + 2) / 2 <= e) ++ti;
        while (ti * (ti + 1) / 2 > e) --ti;
        int ii = e - ti * (ti + 1) / 2;
        int t0 = ti * 8, i0 = ii * 8;
        float* Zs = smem;                 // [8][516]
        float* Hs = smem + 8 * 516;       // [8][516]
        float* red = smem + 2 * 8 * 516;  // [4][64]
        #pragma unroll
        for (int j = 0; j < 4; ++j) {
            int idx = tid + j * 256;
            int row = idx >> 7, col4 = idx & 127;
            float4 v = ((const float4*)(Z + (t0 + row) * H))[col4];
            *(float4*)&Zs[row * 516 + col4 * 4] = v;
            float4 g = ((const float4*)(HZ + (i0 + row) * H))[col4];
            *(float4*)&Hs[row * 516 + col4 * 4] = g;
        }
        __syncthreads();
        int ks = tid >> 6, r = (tid >> 3) & 7, ci = tid & 7;
        float acc = 0.f;
        int kb = ks * 128;
        #pragma unroll 4
        for (int k0 = kb; k0 < kb + 128; k0 += 8) {
            float4 z0 = *(float4*)&Zs[r * 516 + k0];
            float4 z1 = *(float4*)&Zs[r * 516 + k0 + 4];
            float4 h0 = *(float4*)&Hs[ci * 516 + k0];
            float4 h1 = *(float4*)&Hs[ci * 516 + k0 + 4];
            acc += z0.x * h0.x + z0.y * h0.y + z0.z * h0.z + z0.w * h0.w
                 + z1.x * h1.x + z1.y * h1.y + z1.z * h1.z + z1.w * h1.w;
        }
        red[ks * 64 + r * 8 + ci] = acc;
        __syncthreads();
        if (tid < 64) {
            int r2 = tid >> 3, c2 = tid & 7;
            float v = red[tid] + red[64 + tid] + red[128 + tid] + red[192 + tid];
            int t = t0 + r2, i = i0 + c2;
            Beta[t * 256 + i] = (i < t) ? v + c[i] : 0.f;
        }
    }
}

// Per-row t: y=LN(u0), g=softmax(y)-onehot, D=LN-backward(g), SD=S.*D
__global__ __launch_bounds__(256) void k3(
        const float* __restrict__ u0, const float* __restrict__ gamma,
        const float* __restrict__ beta, const int* __restrict__ targets,
        const float* __restrict__ S, float* __restrict__ D, float* __restrict__ SD) {
    __shared__ float s4[4];
    int t = blockIdx.x, tid = threadIdx.x;
    float2 uv = ((const float2*)u0)[t * 256 + tid];
    float2 gv = ((const float2*)gamma)[tid];
    float2 bv = ((const float2*)beta)[tid];

    float m = block_sum(uv.x + uv.y, s4) * (1.f / H);
    float d0 = uv.x - m, d1 = uv.y - m;
    float var = block_sum(d0 * d0 + d1 * d1, s4) * (1.f / H);
    float s = rsqrtf(var + EPSF);
    float xh0 = d0 * s, xh1 = d1 * s;
    float y0 = xh0 * gv.x + bv.x;
    float y1 = xh1 * gv.y + bv.y;

    float ymax = block_max(fmaxf(y0, y1), s4);
    float e0 = __expf(y0 - ymax), e1 = __expf(y1 - ymax);
    float Zs = block_sum(e0 + e1, s4);
    float invZ = 1.f / Zs;
    int tgt = targets[t];
    float g0 = e0 * invZ - (2 * tid == tgt ? 1.f : 0.f);
    float g1 = e1 * invZ - (2 * tid + 1 == tgt ? 1.f : 0.f);
    float gy0 = g0 * gv.x, gy1 = g1 * gv.y;

    float mgy = block_sum(gy0 + gy1, s4) * (1.f / H);
    float mgx = block_sum(gy0 * xh0 + gy1 * xh1, s4) * (1.f / H);

    float dd0 = s * (gy0 - mgy - xh0 * mgx);
    float dd1 = s * (gy1 - mgy - xh1 * mgx);
    float2 sv = ((const float2*)S)[t * 256 + tid];
    ((float2*)D)[t * 256 + tid]  = make_float2(dd0, dd1);
    ((float2*)SD)[t * 256 + tid] = make_float2(sv.x * dd0, sv.y * dd1);
}

// k4a: pre = u0 - S.*(Beta@D) + Beta@SD, col-split GEMM.
// 256 blocks: (row-group R0=8*(bid>>3), col-group g=bid&7 -> 32 float2 cols).
__global__ __launch_bounds__(256) void k4a(
        const float* __restrict__ Beta, const float* __restrict__ D,
        const float* __restrict__ SD, const float* __restrict__ u0,
        const float* __restrict__ S, float* __restrict__ pre) {
    __shared__ float Brow[8][256];      // 8 KB
    __shared__ float2 red1[8][8][32];   // 16 KB
    __shared__ float2 red2[8][8][32];   // 16 KB
    int bid = blockIdx.x, tid = threadIdx.x;
    int R0 = (bid >> 3) * 8;
    int g  = bid & 7;
    #pragma unroll
    for (int j = 0; j < 8; ++j) {
        int idx = tid + j * 256;
        int r = idx >> 8, ci = idx & 255;
        Brow[r][ci] = Beta[(R0 + r) * 256 + ci];
    }
    __syncthreads();

    int ks = tid >> 5, cc = tid & 31;
    int qc = g * 32 + cc;
    int kend = R0 + 8;
    float2 a1[8], a2[8];
    #pragma unroll
    for (int r = 0; r < 8; ++r) { a1[r] = make_float2(0.f, 0.f); a2[r] = make_float2(0.f, 0.f); }
    const float2* D2 = (const float2*)D;
    const float2* SD2 = (const float2*)SD;
    for (int i0 = ks * 8; i0 < kend; i0 += 64) {
        float2 dv[8], sv[8];
        #pragma unroll
        for (int u = 0; u < 8; ++u) {
            dv[u] = D2[(i0 + u) * 256 + qc];
            sv[u] = SD2[(i0 + u) * 256 + qc];
        }
        #pragma unroll
        for (int u = 0; u < 8; ++u) {
            #pragma unroll
            for (int r = 0; r < 8; ++r) {
                float bw = Brow[r][i0 + u];         // wave-broadcast LDS read
                a1[r].x += bw * dv[u].x; a1[r].y += bw * dv[u].y;
                a2[r].x += bw * sv[u].x; a2[r].y += bw * sv[u].y;
            }
        }
    }
    #pragma unroll
    for (int r = 0; r < 8; ++r) { red1[ks][r][cc] = a1[r]; red2[ks][r][cc] = a2[r]; }
    __syncthreads();

    {
        int r = tid >> 5, cL = tid & 31;
        float2 A1 = make_float2(0.f, 0.f), A2 = make_float2(0.f, 0.f);
        #pragma unroll
        for (int p = 0; p < 8; ++p) {
            float2 v1 = red1[p][r][cL], v2 = red2[p][r][cL];
            A1.x += v1.x; A1.y += v1.y;
            A2.x += v2.x; A2.y += v2.y;
        }
        int t = R0 + r;
        int col = g * 32 + cL;
        float2 uv = ((const float2*)u0)[t * 256 + col];
        float2 sv = ((const float2*)S)[t * 256 + col];
        float2 p;
        p.x = uv.x - sv.x * A1.x + A2.x;
        p.y = uv.y - sv.y * A1.y + A2.y;
        ((float2*)pre)[t * 256 + col] = p;
    }
}

// k4b: out = LN(pre) per row, 256 thr/row.
__global__ __launch_bounds__(256) void k4b(
        const float* __restrict__ pre, const float* __restrict__ gamma,
        const float* __restrict__ beta, float* __restrict__ out) {
    __shared__ float s4[4];
    int t = blockIdx.x, tid = threadIdx.x;
    float2 pv = ((const float2*)pre)[t * 256 + tid];
    float m = block_sum(pv.x + pv.y, s4) * (1.f / H);
    float d0 = pv.x - m, d1 = pv.y - m;
    float var = block_sum(d0 * d0 + d1 * d1, s4) * (1.f / H);
    float s = rsqrtf(var + EPSF);
    float2 gv = ((const float2*)gamma)[tid];
    float2 bv = ((const float2*)beta)[tid];
    ((float2*)out)[t * 256 + tid] =
        make_float2(d0 * s * gv.x + bv.x, d1 * s * gv.y + bv.y);
}

extern "C" void kernel_launch(void* const* d_in, const int* in_sizes, int n_in,
                              void* d_out, int out_size, void* d_ws, size_t ws_size,
                              hipStream_t stream) {
    const float* h     = (const float*)d_in[0];
    const float* U     = (const float*)d_in[1];
    const float* W     = (const float*)d_in[2];
    const float* a     = (const float*)d_in[3];
    const float* b     = (const float*)d_in[4];
    const float* gamma = (const float*)d_in[5];
    const float* beta  = (const float*)d_in[6];
    const int*   tgt   = (const int*)d_in[7];
    float* out = (float*)d_out;

    float* ws = (float*)d_ws;
    const int TH = T * H;
    float* Z    = ws;               // TH
    float* HZ   = Z    + TH;
    float* u0   = HZ   + TH;
    float* D    = u0   + TH;
    float* SD   = D    + TH;
    float* S    = SD   + TH;
    float* c    = S    + TH;        // T
    float* Beta = c    + T;         // T*T
    float* pre  = Beta + T * T;     // TH

    k1<<<264, 256, 0, stream>>>(h, U, a, Z, HZ, c, S);
    k2<<<784, 256, 0, stream>>>(Z, W, b, HZ, c, u0, Beta);
    k3<<<T,   256, 0, stream>>>(u0, gamma, beta, tgt, S, D, SD);
    k4a<<<256, 256, 0, stream>>>(Beta, D, SD, u0, S, pre);
    k4b<<<T,  256, 0, stream>>>(pre, gamma, beta, out);
}

// Round 14
// 96.383 us; speedup vs baseline: 1.3251x; 1.0427x over previous
//
#include <hip/hip_runtime.h>

#define T 256
#define H 512
#define EPSF 1e-5f

__device__ __forceinline__ float block_sum(float v, float* s4) {
    for (int o = 32; o; o >>= 1) v += __shfl_xor(v, o);
    int w = threadIdx.x >> 6;
    __syncthreads();
    if ((threadIdx.x & 63) == 0) s4[w] = v;
    __syncthreads();
    return s4[0] + s4[1] + s4[2] + s4[3];
}

__device__ __forceinline__ float block_max(float v, float* s4) {
    for (int o = 32; o; o >>= 1) v = fmaxf(v, __shfl_xor(v, o));
    int w = threadIdx.x >> 6;
    __syncthreads();
    if ((threadIdx.x & 63) == 0) s4[w] = v;
    __syncthreads();
    return fmaxf(fmaxf(s4[0], s4[1]), fmaxf(s4[2], s4[3]));
}

// bid 0..7: S-scan (two-pass, 64 cols/block, wave = 64-t chunk).
// bid 8..263: Z=relu(h@U+a), HZ=h.*Z, c. Tile 8t x 64cols(f2x32), 8-way k-split.
// k4a-pattern: each U-panel load feeds 8 rows -> U traffic 64 -> 32 MB,
// 256 GEMM blocks preserved (32 row-groups x 8 col-groups).
__global__ __launch_bounds__(256) void k1(
        const float* __restrict__ h, const float* __restrict__ U,
        const float* __restrict__ a, float* __restrict__ Z,
        float* __restrict__ HZ, float* __restrict__ c, float* __restrict__ S) {
    __shared__ __align__(16) float smem[8192];   // 32 KB: sh[4096] + red[2048 f2]
    int bid = blockIdx.x, tid = threadIdx.x;
    int lane = tid & 63, w = tid >> 6;
    if (bid < 8) {
        float (*csum)[64] = (float (*)[64])smem;
        int q = bid * 64 + lane;
        int tbase = w * 64;
        float s = 0.f;
        for (int j = 0; j < 64; j += 8) {
            float v[8];
            #pragma unroll
            for (int u = 0; u < 8; ++u) v[u] = h[(tbase + j + u) * H + q];
            #pragma unroll
            for (int u = 0; u < 8; ++u) s += v[u];
        }
        csum[w][lane] = s;
        __syncthreads();
        float acc = 0.f;
        #pragma unroll
        for (int w2 = 0; w2 < 3; ++w2) if (w2 < w) acc += csum[w2][lane];
        for (int j = 0; j < 64; j += 8) {
            float v[8];
            #pragma unroll
            for (int u = 0; u < 8; ++u) v[u] = h[(tbase + j + u) * H + q];
            #pragma unroll
            for (int u = 0; u < 8; ++u) { acc += v[u]; S[(tbase + j + u) * H + q] = acc; }
        }
        return;
    }
    int b = bid - 8;                    // 0..255
    int t0 = (b >> 3) * 8;              // row-group (32)
    int qc0 = (b & 7) * 32;             // col-group base (float2 units)
    float* sh = smem;                   // 8 rows x 512 = 4096 floats
    float2* red = (float2*)(smem + 4096);   // [8 ks][8 r][32 cc]
    #pragma unroll
    for (int j = 0; j < 4; ++j)
        ((float4*)sh)[tid + j * 256] = ((const float4*)(h + t0 * H))[tid + j * 256];
    __syncthreads();

    if ((b & 7) == 0) {                 // c for the 8 staged rows
        int row = 2 * w + (lane >> 5), l5 = lane & 31;
        float s = 0.f;
        #pragma unroll
        for (int j = 0; j < 16; ++j) s += sh[row * 512 + l5 + j * 32];
        #pragma unroll
        for (int o = 16; o; o >>= 1) s += __shfl_xor(s, o);
        if (l5 == 0) c[t0 + row] = s;
    }

    int ks = tid >> 5, cc = tid & 31;
    int qc = qc0 + cc;
    const float2* U2 = (const float2*)U;
    float2 acc[8];
    #pragma unroll
    for (int r = 0; r < 8; ++r) acc[r] = make_float2(0.f, 0.f);
    int kbeg = ks * 64;
    for (int k0 = kbeg; k0 < kbeg + 64; k0 += 8) {
        float2 bv[8];
        #pragma unroll
        for (int u = 0; u < 8; ++u) bv[u] = U2[(k0 + u) * 256 + qc];
        #pragma unroll
        for (int r = 0; r < 8; ++r) {
            float4 a0 = *(float4*)&sh[r * 512 + k0];
            float4 a1 = *(float4*)&sh[r * 512 + k0 + 4];
            acc[r].x += a0.x * bv[0].x + a0.y * bv[1].x + a0.z * bv[2].x + a0.w * bv[3].x
                      + a1.x * bv[4].x + a1.y * bv[5].x + a1.z * bv[6].x + a1.w * bv[7].x;
            acc[r].y += a0.x * bv[0].y + a0.y * bv[1].y + a0.z * bv[2].y + a0.w * bv[3].y
                      + a1.x * bv[4].y + a1.y * bv[5].y + a1.z * bv[6].y + a1.w * bv[7].y;
        }
    }
    #pragma unroll
    for (int r = 0; r < 8; ++r) red[(ks * 8 + r) * 32 + cc] = acc[r];
    __syncthreads();

    {
        int r = tid >> 5, cL = tid & 31;
        float2 A = make_float2(0.f, 0.f);
        #pragma unroll
        for (int p = 0; p < 8; ++p) {
            float2 v = red[(p * 8 + r) * 32 + cL];
            A.x += v.x; A.y += v.y;
        }
        int col = qc0 + cL;
        float2 av2 = ((const float2*)a)[col];
        float zx = fmaxf(A.x + av2.x, 0.f), zy = fmaxf(A.y + av2.y, 0.f);
        float2 hv = ((float2*)sh)[r * 256 + col];
        ((float2*)Z)[(t0 + r) * 256 + col]  = make_float2(zx, zy);
        ((float2*)HZ)[(t0 + r) * 256 + col] = make_float2(hv.x * zx, hv.y * zy);
    }
}

// bid 0..255: u0 = Z@W + b (tile 8t x 64cols, 8-way k-split, k4a pattern).
// bid 256..783: Beta = tril(Z@HZ^T,-1)+c, compact triangular 8x8 tiles.
__global__ __launch_bounds__(256) void k2(
        const float* __restrict__ Z, const float* __restrict__ W,
        const float* __restrict__ bb, const float* __restrict__ HZ,
        const float* __restrict__ c, float* __restrict__ u0,
        float* __restrict__ Beta) {
    __shared__ __align__(16) float smem[2 * 8 * 516 + 256];
    int bid = blockIdx.x, tid = threadIdx.x;
    if (bid < 256) {
        int t0 = (bid >> 3) * 8;
        int qc0 = (bid & 7) * 32;
        float* sh = smem;                       // 4096 floats
        float2* red = (float2*)(smem + 4096);   // 2048 float2
        #pragma unroll
        for (int j = 0; j < 4; ++j)
            ((float4*)sh)[tid + j * 256] = ((const float4*)(Z + t0 * H))[tid + j * 256];
        __syncthreads();

        int ks = tid >> 5, cc = tid & 31;
        int qc = qc0 + cc;
        const float2* W2 = (const float2*)W;
        float2 acc[8];
        #pragma unroll
        for (int r = 0; r < 8; ++r) acc[r] = make_float2(0.f, 0.f);
        int kbeg = ks * 64;
        for (int k0 = kbeg; k0 < kbeg + 64; k0 += 8) {
            float2 bv[8];
            #pragma unroll
            for (int u = 0; u < 8; ++u) bv[u] = W2[(k0 + u) * 256 + qc];
            #pragma unroll
            for (int r = 0; r < 8; ++r) {
                float4 a0 = *(float4*)&sh[r * 512 + k0];
                float4 a1 = *(float4*)&sh[r * 512 + k0 + 4];
                acc[r].x += a0.x * bv[0].x + a0.y * bv[1].x + a0.z * bv[2].x + a0.w * bv[3].x
                          + a1.x * bv[4].x + a1.y * bv[5].x + a1.z * bv[6].x + a1.w * bv[7].x;
                acc[r].y += a0.x * bv[0].y + a0.y * bv[1].y + a0.z * bv[2].y + a0.w * bv[3].y
                          + a1.x * bv[4].y + a1.y * bv[5].y + a1.z * bv[6].y + a1.w * bv[7].y;
            }
        }
        #pragma unroll
        for (int r = 0; r < 8; ++r) red[(ks * 8 + r) * 32 + cc] = acc[r];
        __syncthreads();

        {
            int r = tid >> 5, cL = tid & 31;
            float2 A = make_float2(0.f, 0.f);
            #pragma unroll
            for (int p = 0; p < 8; ++p) {
                float2 v = red[(p * 8 + r) * 32 + cL];
                A.x += v.x; A.y += v.y;
            }
            int col = qc0 + cL;
            float2 bv2 = ((const float2*)bb)[col];
            ((float2*)u0)[(t0 + r) * 256 + col] =
                make_float2(A.x + bv2.x, A.y + bv2.y);
        }
    } else {
        int e = bid - 256;                         // 0..527 compact triangular
        int ti = (int)((sqrtf(8.f * (float)e + 1.f) - 1.f) * 0.5f);
        while ((ti + 1) * (ti + 2) / 2 <= e) ++ti;
        while (ti * (ti + 1) / 2 > e) --ti;
        int ii = e - ti * (ti + 1) / 2;
        int t0 = ti * 8, i0 = ii * 8;
        float* Zs = smem;                 // [8][516]
        float* Hs = smem + 8 * 516;       // [8][516]
        float* red = smem + 2 * 8 * 516;  // [4][64]
        int tid2 = tid;
        #pragma unroll
        for (int j = 0; j < 4; ++j) {
            int idx = tid2 + j * 256;
            int row = idx >> 7, col4 = idx & 127;
            float4 v = ((const float4*)(Z + (t0 + row) * H))[col4];
            *(float4*)&Zs[row * 516 + col4 * 4] = v;
            float4 g = ((const float4*)(HZ + (i0 + row) * H))[col4];
            *(float4*)&Hs[row * 516 + col4 * 4] = g;
        }
        __syncthreads();
        int ks = tid >> 6, r = (tid >> 3) & 7, ci = tid & 7;
        float acc = 0.f;
        int kb = ks * 128;
        #pragma unroll 4
        for (int k0 = kb; k0 < kb + 128; k0 += 8) {
            float4 z0 = *(float4*)&Zs[r * 516 + k0];
            float4 z1 = *(float4*)&Zs[r * 516 + k0 + 4];
            float4 h0 = *(float4*)&Hs[ci * 516 + k0];
            float4 h1 = *(float4*)&Hs[ci * 516 + k0 + 4];
            acc += z0.x * h0.x + z0.y * h0.y + z0.z * h0.z + z0.w * h0.w
                 + z1.x * h1.x + z1.y * h1.y + z1.z * h1.z + z1.w * h1.w;
        }
        red[ks * 64 + r * 8 + ci] = acc;
        __syncthreads();
        if (tid < 64) {
            int r2 = tid >> 3, c2 = tid & 7;
            float v = red[tid] + red[64 + tid] + red[128 + tid] + red[192 + tid];
            int t = t0 + r2, i = i0 + c2;
            Beta[t * 256 + i] = (i < t) ? v + c[i] : 0.f;
        }
    }
}

// Per-row t: y=LN(u0), g=softmax(y)-onehot, D=LN-backward(g), SD=S.*D
__global__ __launch_bounds__(256) void k3(
        const float* __restrict__ u0, const float* __restrict__ gamma,
        const float* __restrict__ beta, const int* __restrict__ targets,
        const float* __restrict__ S, float* __restrict__ D, float* __restrict__ SD) {
    __shared__ float s4[4];
    int t = blockIdx.x, tid = threadIdx.x;
    float2 uv = ((const float2*)u0)[t * 256 + tid];
    float2 gv = ((const float2*)gamma)[tid];
    float2 bv = ((const float2*)beta)[tid];

    float m = block_sum(uv.x + uv.y, s4) * (1.f / H);
    float d0 = uv.x - m, d1 = uv.y - m;
    float var = block_sum(d0 * d0 + d1 * d1, s4) * (1.f / H);
    float s = rsqrtf(var + EPSF);
    float xh0 = d0 * s, xh1 = d1 * s;
    float y0 = xh0 * gv.x + bv.x;
    float y1 = xh1 * gv.y + bv.y;

    float ymax = block_max(fmaxf(y0, y1), s4);
    float e0 = __expf(y0 - ymax), e1 = __expf(y1 - ymax);
    float Zs = block_sum(e0 + e1, s4);
    float invZ = 1.f / Zs;
    int tgt = targets[t];
    float g0 = e0 * invZ - (2 * tid == tgt ? 1.f : 0.f);
    float g1 = e1 * invZ - (2 * tid + 1 == tgt ? 1.f : 0.f);
    float gy0 = g0 * gv.x, gy1 = g1 * gv.y;

    float mgy = block_sum(gy0 + gy1, s4) * (1.f / H);
    float mgx = block_sum(gy0 * xh0 + gy1 * xh1, s4) * (1.f / H);

    float dd0 = s * (gy0 - mgy - xh0 * mgx);
    float dd1 = s * (gy1 - mgy - xh1 * mgx);
    float2 sv = ((const float2*)S)[t * 256 + tid];
    ((float2*)D)[t * 256 + tid]  = make_float2(dd0, dd1);
    ((float2*)SD)[t * 256 + tid] = make_float2(sv.x * dd0, sv.y * dd1);
}

// k4a: pre = u0 - S.*(Beta@D) + Beta@SD, col-split GEMM.
// 256 blocks: (row-group R0=8*(bid>>3), col-group g=bid&7 -> 32 float2 cols).
__global__ __launch_bounds__(256) void k4a(
        const float* __restrict__ Beta, const float* __restrict__ D,
        const float* __restrict__ SD, const float* __restrict__ u0,
        const float* __restrict__ S, float* __restrict__ pre) {
    __shared__ float Brow[8][256];      // 8 KB
    __shared__ float2 red1[8][8][32];   // 16 KB
    __shared__ float2 red2[8][8][32];   // 16 KB
    int bid = blockIdx.x, tid = threadIdx.x;
    int R0 = (bid >> 3) * 8;
    int g  = bid & 7;
    #pragma unroll
    for (int j = 0; j < 8; ++j) {
        int idx = tid + j * 256;
        int r = idx >> 8, ci = idx & 255;
        Brow[r][ci] = Beta[(R0 + r) * 256 + ci];
    }
    __syncthreads();

    int ks = tid >> 5, cc = tid & 31;
    int qc = g * 32 + cc;
    int kend = R0 + 8;
    float2 a1[8], a2[8];
    #pragma unroll
    for (int r = 0; r < 8; ++r) { a1[r] = make_float2(0.f, 0.f); a2[r] = make_float2(0.f, 0.f); }
    const float2* D2 = (const float2*)D;
    const float2* SD2 = (const float2*)SD;
    for (int i0 = ks * 8; i0 < kend; i0 += 64) {
        float2 dv[8], sv[8];
        #pragma unroll
        for (int u = 0; u < 8; ++u) {
            dv[u] = D2[(i0 + u) * 256 + qc];
            sv[u] = SD2[(i0 + u) * 256 + qc];
        }
        #pragma unroll
        for (int u = 0; u < 8; ++u) {
            #pragma unroll
            for (int r = 0; r < 8; ++r) {
                float bw = Brow[r][i0 + u];         // wave-broadcast LDS read
                a1[r].x += bw * dv[u].x; a1[r].y += bw * dv[u].y;
                a2[r].x += bw * sv[u].x; a2[r].y += bw * sv[u].y;
            }
        }
    }
    #pragma unroll
    for (int r = 0; r < 8; ++r) { red1[ks][r][cc] = a1[r]; red2[ks][r][cc] = a2[r]; }
    __syncthreads();

    {
        int r = tid >> 5, cL = tid & 31;
        float2 A1 = make_float2(0.f, 0.f), A2 = make_float2(0.f, 0.f);
        #pragma unroll
        for (int p = 0; p < 8; ++p) {
            float2 v1 = red1[p][r][cL], v2 = red2[p][r][cL];
            A1.x += v1.x; A1.y += v1.y;
            A2.x += v2.x; A2.y += v2.y;
        }
        int t = R0 + r;
        int col = g * 32 + cL;
        float2 uv = ((const float2*)u0)[t * 256 + col];
        float2 sv = ((const float2*)S)[t * 256 + col];
        float2 p;
        p.x = uv.x - sv.x * A1.x + A2.x;
        p.y = uv.y - sv.y * A1.y + A2.y;
        ((float2*)pre)[t * 256 + col] = p;
    }
}

// k4b: out = LN(pre) per row, 256 thr/row.
__global__ __launch_bounds__(256) void k4b(
        const float* __restrict__ pre, const float* __restrict__ gamma,
        const float* __restrict__ beta, float* __restrict__ out) {
    __shared__ float s4[4];
    int t = blockIdx.x, tid = threadIdx.x;
    float2 pv = ((const float2*)pre)[t * 256 + tid];
    float m = block_sum(pv.x + pv.y, s4) * (1.f / H);
    float d0 = pv.x - m, d1 = pv.y - m;
    float var = block_sum(d0 * d0 + d1 * d1, s4) * (1.f / H);
    float s = rsqrtf(var + EPSF);
    float2 gv = ((const float2*)gamma)[tid];
    float2 bv = ((const float2*)beta)[tid];
    ((float2*)out)[t * 256 + tid] =
        make_float2(d0 * s * gv.x + bv.x, d1 * s * gv.y + bv.y);
}

extern "C" void kernel_launch(void* const* d_in, const int* in_sizes, int n_in,
                              void* d_out, int out_size, void* d_ws, size_t ws_size,
                              hipStream_t stream) {
    const float* h     = (const float*)d_in[0];
    const float* U     = (const float*)d_in[1];
    const float* W     = (const float*)d_in[2];
    const float* a     = (const float*)d_in[3];
    const float* b     = (const float*)d_in[4];
    const float* gamma = (const float*)d_in[5];
    const float* beta  = (const float*)d_in[6];
    const int*   tgt   = (const int*)d_in[7];
    float* out = (float*)d_out;

    float* ws = (float*)d_ws;
    const int TH = T * H;
    float* Z    = ws;               // TH
    float* HZ   = Z    + TH;
    float* u0   = HZ   + TH;
    float* D    = u0   + TH;
    float* SD   = D    + TH;
    float* S    = SD   + TH;
    float* c    = S    + TH;        // T
    float* Beta = c    + T;         // T*T
    float* pre  = Beta + T * T;     // TH

    k1<<<264, 256, 0, stream>>>(h, U, a, Z, HZ, c, S);
    k2<<<784, 256, 0, stream>>>(Z, W, b, HZ, c, u0, Beta);
    k3<<<T,   256, 0, stream>>>(u0, gamma, beta, tgt, S, D, SD);
    k4a<<<256, 256, 0, stream>>>(Beta, D, SD, u0, S, pre);
    k4b<<<T,  256, 0, stream>>>(pre, gamma, beta, out);
}